// Round 5
// baseline (139.930 us; speedup 1.0000x reference)
//
#include <hip/hip_runtime.h>

// KLD RepPoints loss, R4: pair-batched float4 gather, two-kernel reduce.
// History: R0/R1 sat on a 60us single-line atomicAdd floor (WRITE_SIZE=128KB
// gave it away). R2 (block partials -> ws, no atomics) = best, ~37us kernels.
// R3 (LDS staging) regressed -> per-instruction line fan-out is NOT the
// limiter. Current theory: 8B float2 requests waste the L1/L2 request path
// (26 requests/elem-pair). Fix: thread owns TWO consecutive elements --
// pred pair = 144B = 9x float4 (16B aligned), target pair = 4x float4.
// 13 requests per 2 elements, 16B each: 2x fewer requests, 2x payload.
// No LDS, no extra syncs, no atomics.

__device__ __forceinline__ float kld_elem(
    const float* px, const float* py,
    float tx0, float ty0, float tx1, float ty1,
    float tx2, float ty2, float tx3, float ty3)
{
    // ---- pred moments ----
    const float inv9 = 1.0f / 9.0f;
    float sx = 0.f, sy = 0.f;
    #pragma unroll
    for (int k = 0; k < 9; ++k) { sx += px[k]; sy += py[k]; }
    float mux = sx * inv9, muy = sy * inv9;
    float a = 0.f, b = 0.f, d = 0.f;   // p_var = [[a,b],[b,d]]
    #pragma unroll
    for (int k = 0; k < 9; ++k) {
        float xx = px[k] - mux, yy = py[k] - muy;
        a += xx * xx; b += xx * yy; d += yy * yy;
    }
    a = a * inv9 + 1e-6f;
    b = b * inv9;
    d = d * inv9 + 1e-6f;

    // ---- target box -> rotated Gaussian ----
    float tmux = (tx0 + tx1 + tx2 + tx3) * 0.25f;
    float tmuy = (ty0 + ty1 + ty2 + ty3) * 0.25f;
    float e1x = tx1 - tx0, e1y = ty1 - ty0;
    float e2x = tx2 - tx1, e2y = ty2 - ty1;
    float w = e1x * e1x + e1y * e1y;
    float h = e2x * e2x + e2y * e2y;
    float sw = sqrtf(w);
    float c = e1x / sw, s = e1y / sw;
    const float invLL = 1.0f / 36.0f;      // 1/(4*L*L), L=3
    float dw = w * invLL, dh = h * invLL;
    float tv00 = c * c * dw + s * s * dh;  // t_var = R diag(dw,dh) R^T
    float tv01 = c * s * (dw - dh);
    float tv11 = s * s * dw + c * c * dh;

    float t_det = tv00 * tv11 - tv01 * tv01;
    float p_det = a * d - b * b;
    float inv_tdet = 1.0f / t_det;

    float dx = mux - tmux, dy = muy - tmuy;
    float term1 = (dx * dx * tv11 - 2.0f * dx * dy * tv01 + dy * dy * tv00) * inv_tdet;
    float trace = (tv11 * a - 2.0f * tv01 * b + tv00 * d) * inv_tdet;
    float term2 = trace + logf(t_det / p_det);
    float kld = 0.5f * (term1 + term2) - 1.0f;
    float kl = fmaxf(kld, 1e-6f);
    return 1.0f - 1.0f / (2.0f + sqrtf(kl));
}

__global__ __launch_bounds__(256) void kld_partial_kernel(
    const float* __restrict__ pred,    // [n][9][2]
    const float* __restrict__ target,  // [n][4][2]
    float* __restrict__ ws,            // [gridDim.x] partial sums
    int n_total)
{
    const int tid = blockIdx.x * 256 + threadIdx.x;
    const int npairs = n_total >> 1;

    float loss = 0.0f;
    if (tid < npairs) {
        // pred pair: 144B = 9 x float4, base 144B*tid is 16B-aligned
        const float4* pp = reinterpret_cast<const float4*>(pred) + (size_t)tid * 9;
        float4 f0 = pp[0], f1 = pp[1], f2 = pp[2], f3 = pp[3], f4 = pp[4],
               f5 = pp[5], f6 = pp[6], f7 = pp[7], f8 = pp[8];
        // target pair: 64B = 4 x float4
        const float4* tt = reinterpret_cast<const float4*>(target) + (size_t)tid * 4;
        float4 g0 = tt[0], g1 = tt[1], g2 = tt[2], g3 = tt[3];

        float px[9], py[9];
        // element 2*tid
        px[0] = f0.x; py[0] = f0.y;  px[1] = f0.z; py[1] = f0.w;
        px[2] = f1.x; py[2] = f1.y;  px[3] = f1.z; py[3] = f1.w;
        px[4] = f2.x; py[4] = f2.y;  px[5] = f2.z; py[5] = f2.w;
        px[6] = f3.x; py[6] = f3.y;  px[7] = f3.z; py[7] = f3.w;
        px[8] = f4.x; py[8] = f4.y;
        loss += kld_elem(px, py, g0.x, g0.y, g0.z, g0.w, g1.x, g1.y, g1.z, g1.w);
        // element 2*tid+1
        px[0] = f4.z; py[0] = f4.w;
        px[1] = f5.x; py[1] = f5.y;  px[2] = f5.z; py[2] = f5.w;
        px[3] = f6.x; py[3] = f6.y;  px[4] = f6.z; py[4] = f6.w;
        px[5] = f7.x; py[5] = f7.y;  px[6] = f7.z; py[6] = f7.w;
        px[7] = f8.x; py[7] = f8.y;  px[8] = f8.z; py[8] = f8.w;
        loss += kld_elem(px, py, g2.x, g2.y, g2.z, g2.w, g3.x, g3.y, g3.z, g3.w);
    }

    // odd-n tail element (not taken for n_total even)
    if ((n_total & 1) && tid == 0) {
        int n = n_total - 1;
        const float2* p = reinterpret_cast<const float2*>(pred + (size_t)n * 18);
        float px[9], py[9];
        #pragma unroll
        for (int k = 0; k < 9; ++k) { float2 v = p[k]; px[k] = v.x; py[k] = v.y; }
        const float2* t = reinterpret_cast<const float2*>(target + (size_t)n * 8);
        float2 t0 = t[0], t1 = t[1], t2 = t[2], t3 = t[3];
        loss += kld_elem(px, py, t0.x, t0.y, t1.x, t1.y, t2.x, t2.y, t3.x, t3.y);
    }

    // ---- reduction: wave64 shuffle -> LDS -> one plain store per block ----
    #pragma unroll
    for (int off = 32; off > 0; off >>= 1)
        loss += __shfl_down(loss, off, 64);

    __shared__ float sm[4];
    int lane = threadIdx.x & 63;
    int wid  = threadIdx.x >> 6;
    if (lane == 0) sm[wid] = loss;
    __syncthreads();
    if (threadIdx.x == 0)
        ws[blockIdx.x] = sm[0] + sm[1] + sm[2] + sm[3];
}

__global__ __launch_bounds__(256) void kld_final_kernel(
    const float* __restrict__ ws, float* __restrict__ out,
    int nblocks, float inv_n)
{
    float s = 0.0f;
    for (int i = threadIdx.x; i < nblocks; i += 256)
        s += ws[i];

    #pragma unroll
    for (int off = 32; off > 0; off >>= 1)
        s += __shfl_down(s, off, 64);

    __shared__ float sm[4];
    int lane = threadIdx.x & 63;
    int wid  = threadIdx.x >> 6;
    if (lane == 0) sm[wid] = s;
    __syncthreads();
    if (threadIdx.x == 0)
        out[0] = (sm[0] + sm[1] + sm[2] + sm[3]) * inv_n;
}

extern "C" void kernel_launch(void* const* d_in, const int* in_sizes, int n_in,
                              void* d_out, int out_size, void* d_ws, size_t ws_size,
                              hipStream_t stream) {
    const float* pred   = (const float*)d_in[0];
    const float* target = (const float*)d_in[1];
    float* out = (float*)d_out;
    float* ws  = (float*)d_ws;

    int n = in_sizes[0] / 18;       // N elements (pred is N*9*2 floats)
    int npairs = n >> 1;
    int nblocks = (npairs + 255) / 256;
    if (nblocks < 1) nblocks = 1;

    kld_partial_kernel<<<nblocks, 256, 0, stream>>>(pred, target, ws, n);
    kld_final_kernel<<<1, 256, 0, stream>>>(ws, out, nblocks, 1.0f / (float)n);
}

// Round 6
// 134.168 us; speedup vs baseline: 1.0429x; 1.0429x over previous
//
#include <hip/hip_runtime.h>

// KLD RepPoints loss, R5: 4-element wave-granular batching for MLP.
// History: 60us floor in R0/R1 was 4096 same-line atomicAdds (WRITE_SIZE
// betrayed it); R2 (two-kernel, no atomics) = best at ~32us kernel time.
// R3 (LDS dense staging) and R4 (float4 pair gather) both REGRESSED ->
// request shape doesn't matter; the limiter is one memory round-trip per
// element with only ~13 outstanding 8B loads/thread at ~4 waves/SIMD.
// R5: keep R2's exact float2 pattern (consecutive lanes = consecutive
// elements) but give each thread 4 elements strided by grid size, loads
// fully unrolled so the compiler pipelines up to 52 loads ahead of use.
// Reduction amortized 4x, 1024 blocks, final kernel reads 1024 partials.

__device__ __forceinline__ float kld_elem(
    const float px[9], const float py[9],
    const float tx[4], const float ty[4])
{
    // ---- pred moments ----
    const float inv9 = 1.0f / 9.0f;
    float sx = 0.f, sy = 0.f;
    #pragma unroll
    for (int k = 0; k < 9; ++k) { sx += px[k]; sy += py[k]; }
    float mux = sx * inv9, muy = sy * inv9;
    float a = 0.f, b = 0.f, d = 0.f;   // p_var = [[a,b],[b,d]]
    #pragma unroll
    for (int k = 0; k < 9; ++k) {
        float xx = px[k] - mux, yy = py[k] - muy;
        a += xx * xx; b += xx * yy; d += yy * yy;
    }
    a = a * inv9 + 1e-6f;
    b = b * inv9;
    d = d * inv9 + 1e-6f;

    // ---- target box -> rotated Gaussian ----
    float tmux = (tx[0] + tx[1] + tx[2] + tx[3]) * 0.25f;
    float tmuy = (ty[0] + ty[1] + ty[2] + ty[3]) * 0.25f;
    float e1x = tx[1] - tx[0], e1y = ty[1] - ty[0];
    float e2x = tx[2] - tx[1], e2y = ty[2] - ty[1];
    float w = e1x * e1x + e1y * e1y;
    float h = e2x * e2x + e2y * e2y;
    float sw = sqrtf(w);
    float c = e1x / sw, s = e1y / sw;
    const float invLL = 1.0f / 36.0f;      // 1/(4*L*L), L=3
    float dw = w * invLL, dh = h * invLL;
    float tv00 = c * c * dw + s * s * dh;  // t_var = R diag(dw,dh) R^T
    float tv01 = c * s * (dw - dh);
    float tv11 = s * s * dw + c * c * dh;

    float t_det = tv00 * tv11 - tv01 * tv01;
    float p_det = a * d - b * b;
    float inv_tdet = 1.0f / t_det;

    float dx = mux - tmux, dy = muy - tmuy;
    float term1 = (dx * dx * tv11 - 2.0f * dx * dy * tv01 + dy * dy * tv00) * inv_tdet;
    float trace = (tv11 * a - 2.0f * tv01 * b + tv00 * d) * inv_tdet;
    float term2 = trace + logf(t_det / p_det);
    float kld = 0.5f * (term1 + term2) - 1.0f;
    float kl = fmaxf(kld, 1e-6f);
    return 1.0f - 1.0f / (2.0f + sqrtf(kl));
}

#define ELEMS_PER_THREAD 4

__global__ __launch_bounds__(256) void kld_partial_kernel(
    const float* __restrict__ pred,    // [n][9][2]
    const float* __restrict__ target,  // [n][4][2]
    float* __restrict__ ws,            // [gridDim.x] partial sums
    int n_total)
{
    const int idx0   = blockIdx.x * 256 + threadIdx.x;
    const int stride = gridDim.x * 256;

    float loss = 0.0f;

    #pragma unroll
    for (int i = 0; i < ELEMS_PER_THREAD; ++i) {
        int e = idx0 + i * stride;
        if (e < n_total) {
            const float2* p = reinterpret_cast<const float2*>(pred) + (size_t)e * 9;
            const float2* t = reinterpret_cast<const float2*>(target) + (size_t)e * 4;
            float2 p0 = p[0], p1 = p[1], p2 = p[2], p3 = p[3], p4 = p[4],
                   p5 = p[5], p6 = p[6], p7 = p[7], p8 = p[8];
            float2 q0 = t[0], q1 = t[1], q2 = t[2], q3 = t[3];

            float px[9] = {p0.x, p1.x, p2.x, p3.x, p4.x, p5.x, p6.x, p7.x, p8.x};
            float py[9] = {p0.y, p1.y, p2.y, p3.y, p4.y, p5.y, p6.y, p7.y, p8.y};
            float tx[4] = {q0.x, q1.x, q2.x, q3.x};
            float ty[4] = {q0.y, q1.y, q2.y, q3.y};
            loss += kld_elem(px, py, tx, ty);
        }
    }

    // ---- reduction: wave64 shuffle -> LDS -> one plain store per block ----
    #pragma unroll
    for (int off = 32; off > 0; off >>= 1)
        loss += __shfl_down(loss, off, 64);

    __shared__ float sm[4];
    int lane = threadIdx.x & 63;
    int wid  = threadIdx.x >> 6;
    if (lane == 0) sm[wid] = loss;
    __syncthreads();
    if (threadIdx.x == 0)
        ws[blockIdx.x] = sm[0] + sm[1] + sm[2] + sm[3];
}

__global__ __launch_bounds__(256) void kld_final_kernel(
    const float* __restrict__ ws, float* __restrict__ out,
    int nblocks, float inv_n)
{
    float s = 0.0f;
    for (int i = threadIdx.x; i < nblocks; i += 256)
        s += ws[i];

    #pragma unroll
    for (int off = 32; off > 0; off >>= 1)
        s += __shfl_down(s, off, 64);

    __shared__ float sm[4];
    int lane = threadIdx.x & 63;
    int wid  = threadIdx.x >> 6;
    if (lane == 0) sm[wid] = s;
    __syncthreads();
    if (threadIdx.x == 0)
        out[0] = (sm[0] + sm[1] + sm[2] + sm[3]) * inv_n;
}

extern "C" void kernel_launch(void* const* d_in, const int* in_sizes, int n_in,
                              void* d_out, int out_size, void* d_ws, size_t ws_size,
                              hipStream_t stream) {
    const float* pred   = (const float*)d_in[0];
    const float* target = (const float*)d_in[1];
    float* out = (float*)d_out;
    float* ws  = (float*)d_ws;

    int n = in_sizes[0] / 18;   // N elements (pred is N*9*2 floats)
    int nblocks = (n + 256 * ELEMS_PER_THREAD - 1) / (256 * ELEMS_PER_THREAD);
    if (nblocks < 1) nblocks = 1;

    kld_partial_kernel<<<nblocks, 256, 0, stream>>>(pred, target, ws, n);
    kld_final_kernel<<<1, 256, 0, stream>>>(ws, out, nblocks, 1.0f / (float)n);
}